// Round 9
// baseline (159.557 us; speedup 1.0000x reference)
//
#include <hip/hip_runtime.h>
#include <hip/hip_bf16.h>

// All reference dtypes are float32 (verified R3): inputs const float*, output float*.

#define BATCH 2
#define NTOK 9216        // 96*96
#define CCH 64
#define DV 32
#define KS 4                          // key splits (per block; x4 waves -> eff 16)
#define KEYS_PER_BLOCK (NTOK / KS)    // 2304
#define KEYS_PER_WAVE (KEYS_PER_BLOCK / 4)  // 576 (per wave)
#define KT 32                         // keys per MFMA tile
#define NKT (KEYS_PER_WAVE / KT)      // 18 tiles per wave
#define ROWS (BATCH * NTOK)           // 18432
#define QT (ROWS / 32)                // 576 query tiles (32 q per block)
#define LOG2E 1.44269504088896340736f
#define PB 32                         // proj rows per block

typedef __attribute__((ext_vector_type(8))) short bf16x8;   // 8 bf16 (4 VGPRs)
typedef __attribute__((ext_vector_type(4))) float f32x4;    // MFMA C/D

__device__ __forceinline__ short f2bf(float x) {
    __hip_bfloat16 h = __float2bfloat16(x);   // RNE
    return *(short*)&h;
}
__device__ __forceinline__ float bf2f(short s) {
    unsigned u = ((unsigned)(unsigned short)s) << 16;
    return *(float*)&u;
}

// ---------------------------------------------------------------------------
// Kernel 1: projections -> MFMA-ready bf16 operands + zeroing of l/o_acc.
//  gx[row][32]: [g_hi(8) | g_lo(8) | g_hi(8) | 0]   (g pre-scaled by log2e)
//  fx[key][32]: [f_hi(8) | f_hi(8) | f_lo(8) | 0]
//  hT[b][v][k_pv]: transposed H with keys permuted within each 32-key tile:
//   np(ni) = ((ni&15)>>2)*8 + (ni&3) + ((ni>>4)&1)*4  — makes post-exp2 P
//   registers directly usable as the PV A-frag (verified R8).
// Phase-1 branch is wave-uniform: waves 0-1 compute f, waves 2-3 compute g.
// ---------------------------------------------------------------------------
__global__ __launch_bounds__(512) void proj_kernel(
    const float* __restrict__ x,
    const float* __restrict__ W1, const float* __restrict__ b1,
    const float* __restrict__ W2, const float* __restrict__ b2,
    const float* __restrict__ W3, const float* __restrict__ b3,
    short* __restrict__ fx, short* __restrict__ gx, short* __restrict__ hT,
    float4* __restrict__ zbase)
{
    __shared__ float xS[PB][CCH];        // 8 KB
    __shared__ short fgS[2][PB][32];     // 4 KB staging for fx, gx
    __shared__ short hS[32][PB + 2];     // 2.1 KB staging for hT

    const int tid = threadIdx.x;
    const int r0  = blockIdx.x * PB;     // 32-row tile, batch-aligned

    // zero slice of l_acc + o_acc: 152064 float4 total / 576 blocks = 264
    if (tid < 264) zbase[blockIdx.x * 264 + tid] = make_float4(0.f, 0.f, 0.f, 0.f);

    // cooperative x load: 512 threads x float4 = 32 rows x 64 floats
    ((float4*)xS)[tid] = ((const float4*)(x + (size_t)r0 * CCH))[tid];
    __syncthreads();

    // phase 1: f (tid<256) / g (tid>=256) — wave-uniform split
    {
        const int half = tid >> 8;            // 0: f, 1: g
        const int rr   = (tid & 255) >> 3;    // 0..31
        const int c    = tid & 7;             // 0..7
        const float* xr = xS[rr];
        if (half == 0) {
            float acc = b1[c];
            #pragma unroll
            for (int k = 0; k < CCH; ++k) acc += xr[k] * W1[k * 8 + c];
            short hi = f2bf(acc);
            short lo = f2bf(acc - bf2f(hi));
            fgS[0][rr][c] = hi; fgS[0][rr][c + 8] = hi;
            fgS[0][rr][c + 16] = lo; fgS[0][rr][c + 24] = 0;
        } else {
            float acc = b2[c];
            #pragma unroll
            for (int k = 0; k < CCH; ++k) acc += xr[k] * W2[k * 8 + c];
            acc *= LOG2E;                 // fold log2(e) for exp2 inner loop
            short hi = f2bf(acc);
            short lo = f2bf(acc - bf2f(hi));
            fgS[1][rr][c] = hi; fgS[1][rr][c + 8] = lo;
            fgS[1][rr][c + 16] = hi; fgS[1][rr][c + 24] = 0;
        }
    }
    // phase 2: h — thread (c = tid&31, rbase = tid>>5) covers rows rbase, rbase+16
    {
        const int c = tid & 31;
        const int rbase = tid >> 5;
        #pragma unroll
        for (int s = 0; s < 2; ++s) {
            int rr = rbase + s * 16;
            float acc = b3[c];
            #pragma unroll
            for (int k = 0; k < CCH; ++k) acc += xS[rr][k] * W3[k * 32 + c];
            int np = ((rr & 15) >> 2) * 8 + (rr & 3) + ((rr >> 4) & 1) * 4;
            hS[c][np] = f2bf(acc);
        }
    }
    __syncthreads();

    // coalesced write-out (dwords)
    ((int*)(fx + (size_t)r0 * 32))[tid] = ((const int*)fgS[0])[tid];
    ((int*)(gx + (size_t)r0 * 32))[tid] = ((const int*)fgS[1])[tid];
    {
        const int b  = r0 / NTOK;
        const int n0 = r0 - b * NTOK;
        const int c  = tid >> 4;
        const int d  = tid & 15;
        ((int*)(hT + (size_t)(b * 32 + c) * NTOK + n0))[d] = ((const int*)&hS[c][0])[d];
    }
}

// ---------------------------------------------------------------------------
// Kernel 2: MFMA flash attention with ZERO in-loop LDS (R8 loop, 4-wave TLP).
// QK computed transposed (A=f-ext, B=g-ext): lane holds S[q=col][k=quad*4+r].
// After exp2, each lane's 8 P values are EXACTLY the PV A-frag under the hT
// key permutation — no LDS round-trip. l per-lane, shfl-reduced.
// Block = 4 waves over the SAME 32 queries, each wave 1/4 of the key split
// (per-wave NKT=18, total waves 9216 = 9/SIMD -> 8/SIMD resident at cap).
// Epilogue: 3-buffer LDS tree merge, one global-atomic set per block.
// Grid: QT * KS = 576*4 = 2304 blocks.
// ---------------------------------------------------------------------------
__global__ __launch_bounds__(256, 8) void attn_kernel(
    const short* __restrict__ fx, const short* __restrict__ gx,
    const short* __restrict__ hT,
    float* __restrict__ l_acc, float* __restrict__ o_acc)
{
    __shared__ float red[3][32 * 33];         // epilogue-only, 12.7 KB

    const int tid  = threadIdx.x;
    const int wave = tid >> 6;                // 0..3
    const int lane = tid & 63;
    const int col  = lane & 15;
    const int quad = lane >> 4;

    const int blk = blockIdx.x;
    const int qt  = blk % QT;                 // query tile 0..575
    const int ks  = blk / QT;                 // key split 0..3
    const int b   = qt / (QT / BATCH);        // batch
    const int qbase   = (qt % (QT / BATCH)) * 32;
    const int rowbase = b * NTOK + qbase;

    // persistent B-operands for QK: g-ext for 2 query sub-tiles
    const bf16x8 agA = *(const bf16x8*)(gx + (size_t)(rowbase + col) * 32 + quad * 8);
    const bf16x8 agB = *(const bf16x8*)(gx + (size_t)(rowbase + 16 + col) * 32 + quad * 8);

    f32x4 oA0 = {0.f,0.f,0.f,0.f}, oA1 = {0.f,0.f,0.f,0.f};
    f32x4 oB0 = {0.f,0.f,0.f,0.f}, oB1 = {0.f,0.f,0.f,0.f};
    float lA = 0.f, lB = 0.f;
    const f32x4 zero4 = {0.f,0.f,0.f,0.f};

    const int kstart = ks * KEYS_PER_BLOCK + wave * KEYS_PER_WAVE;
    const short* fbase = fx + ((size_t)b * NTOK + kstart) * 32;
    const short* hp0 = hT + ((size_t)(b * 32 + col)) * NTOK + kstart;       // v=col
    const short* hp1 = hT + ((size_t)(b * 32 + 16 + col)) * NTOK + kstart;  // v=16+col

    // preload tile 0
    bf16x8 fa0 = *(const bf16x8*)(fbase + (size_t)col * 32 + quad * 8);        // keys 0-15
    bf16x8 fa1 = *(const bf16x8*)(fbase + (size_t)(16 + col) * 32 + quad * 8); // keys 16-31
    bf16x8 hb0 = *(const bf16x8*)(hp0 + quad * 8);
    bf16x8 hb1 = *(const bf16x8*)(hp1 + quad * 8);

    union PU { int i[4]; bf16x8 v; };

    for (int t = 0; t < NKT; ++t) {
        // QK transposed: lane holds S[q=col][k=quad*4+r]
        f32x4 t00 = __builtin_amdgcn_mfma_f32_16x16x32_bf16(fa0, agA, zero4, 0, 0, 0);
        f32x4 t01 = __builtin_amdgcn_mfma_f32_16x16x32_bf16(fa1, agA, zero4, 0, 0, 0);
        f32x4 t10 = __builtin_amdgcn_mfma_f32_16x16x32_bf16(fa0, agB, zero4, 0, 0, 0);
        f32x4 t11 = __builtin_amdgcn_mfma_f32_16x16x32_bf16(fa1, agB, zero4, 0, 0, 0);

        // prefetch tile t+1 (clamped; discarded on last iter)
        const int kn = (t + 1 < NKT) ? (t + 1) * KT : 0;
        bf16x8 nf0 = *(const bf16x8*)(fbase + (size_t)(kn + col) * 32 + quad * 8);
        bf16x8 nf1 = *(const bf16x8*)(fbase + (size_t)(kn + 16 + col) * 32 + quad * 8);
        bf16x8 nh0 = *(const bf16x8*)(hp0 + kn + quad * 8);
        bf16x8 nh1 = *(const bf16x8*)(hp1 + kn + quad * 8);

        // exp2 + round-to-bf16 + pack: P registers ARE the PV A-frag
        PU pA, pB;
        {
            float e0 = __builtin_amdgcn_exp2f(t00[0]), e1 = __builtin_amdgcn_exp2f(t00[1]);
            float e2 = __builtin_amdgcn_exp2f(t00[2]), e3 = __builtin_amdgcn_exp2f(t00[3]);
            float e4 = __builtin_amdgcn_exp2f(t01[0]), e5 = __builtin_amdgcn_exp2f(t01[1]);
            float e6 = __builtin_amdgcn_exp2f(t01[2]), e7 = __builtin_amdgcn_exp2f(t01[3]);
            lA += (e0 + e1) + (e2 + e3) + (e4 + e5) + (e6 + e7);
            pA.i[0] = (int)__builtin_amdgcn_perm((unsigned)__float_as_int(e1) + 0x8000u,
                                                 (unsigned)__float_as_int(e0) + 0x8000u, 0x07060302u);
            pA.i[1] = (int)__builtin_amdgcn_perm((unsigned)__float_as_int(e3) + 0x8000u,
                                                 (unsigned)__float_as_int(e2) + 0x8000u, 0x07060302u);
            pA.i[2] = (int)__builtin_amdgcn_perm((unsigned)__float_as_int(e5) + 0x8000u,
                                                 (unsigned)__float_as_int(e4) + 0x8000u, 0x07060302u);
            pA.i[3] = (int)__builtin_amdgcn_perm((unsigned)__float_as_int(e7) + 0x8000u,
                                                 (unsigned)__float_as_int(e6) + 0x8000u, 0x07060302u);
        }
        {
            float e0 = __builtin_amdgcn_exp2f(t10[0]), e1 = __builtin_amdgcn_exp2f(t10[1]);
            float e2 = __builtin_amdgcn_exp2f(t10[2]), e3 = __builtin_amdgcn_exp2f(t10[3]);
            float e4 = __builtin_amdgcn_exp2f(t11[0]), e5 = __builtin_amdgcn_exp2f(t11[1]);
            float e6 = __builtin_amdgcn_exp2f(t11[2]), e7 = __builtin_amdgcn_exp2f(t11[3]);
            lB += (e0 + e1) + (e2 + e3) + (e4 + e5) + (e6 + e7);
            pB.i[0] = (int)__builtin_amdgcn_perm((unsigned)__float_as_int(e1) + 0x8000u,
                                                 (unsigned)__float_as_int(e0) + 0x8000u, 0x07060302u);
            pB.i[1] = (int)__builtin_amdgcn_perm((unsigned)__float_as_int(e3) + 0x8000u,
                                                 (unsigned)__float_as_int(e2) + 0x8000u, 0x07060302u);
            pB.i[2] = (int)__builtin_amdgcn_perm((unsigned)__float_as_int(e5) + 0x8000u,
                                                 (unsigned)__float_as_int(e4) + 0x8000u, 0x07060302u);
            pB.i[3] = (int)__builtin_amdgcn_perm((unsigned)__float_as_int(e7) + 0x8000u,
                                                 (unsigned)__float_as_int(e6) + 0x8000u, 0x07060302u);
        }

        // PV: A = packed P (direct), B = permuted hT frags
        oA0 = __builtin_amdgcn_mfma_f32_16x16x32_bf16(pA.v, hb0, oA0, 0, 0, 0);
        oA1 = __builtin_amdgcn_mfma_f32_16x16x32_bf16(pA.v, hb1, oA1, 0, 0, 0);
        oB0 = __builtin_amdgcn_mfma_f32_16x16x32_bf16(pB.v, hb0, oB0, 0, 0, 0);
        oB1 = __builtin_amdgcn_mfma_f32_16x16x32_bf16(pB.v, hb1, oB1, 0, 0, 0);

        fa0 = nf0; fa1 = nf1; hb0 = nh0; hb1 = nh1;
    }

    // l: reduce across quads (lanes col, col+16, col+32, col+48 share q=col)
    lA += __shfl_xor(lA, 16); lA += __shfl_xor(lA, 32);
    lB += __shfl_xor(lB, 16); lB += __shfl_xor(lB, 32);

    // epilogue: waves 1..3 store to red[wave-1]; wave 0 combines + atomics.
    // O layout: lane holds O[q=quad*4+r][v=col] (oX0) / [v=16+col] (oX1).
    if (wave >= 1) {
        float* rw = red[wave - 1];
        #pragma unroll
        for (int r = 0; r < 4; ++r) {
            rw[(quad * 4 + r) * 33 + col]           = oA0[r];
            rw[(quad * 4 + r) * 33 + 16 + col]      = oA1[r];
            rw[(16 + quad * 4 + r) * 33 + col]      = oB0[r];
            rw[(16 + quad * 4 + r) * 33 + 16 + col] = oB1[r];
        }
        if (quad == 0) {
            rw[col * 33 + 32]        = lA;
            rw[(16 + col) * 33 + 32] = lB;
        }
    }
    __syncthreads();
    if (wave == 0) {
        #pragma unroll
        for (int r = 0; r < 4; ++r) {
            int qA = quad * 4 + r, qB = 16 + quad * 4 + r;
            float vA0 = oA0[r] + red[0][qA * 33 + col]      + red[1][qA * 33 + col]      + red[2][qA * 33 + col];
            float vA1 = oA1[r] + red[0][qA * 33 + 16 + col] + red[1][qA * 33 + 16 + col] + red[2][qA * 33 + 16 + col];
            float vB0 = oB0[r] + red[0][qB * 33 + col]      + red[1][qB * 33 + col]      + red[2][qB * 33 + col];
            float vB1 = oB1[r] + red[0][qB * 33 + 16 + col] + red[1][qB * 33 + 16 + col] + red[2][qB * 33 + 16 + col];
            atomicAdd(&o_acc[(size_t)(rowbase + qA) * 32 + col],      vA0);
            atomicAdd(&o_acc[(size_t)(rowbase + qA) * 32 + 16 + col], vA1);
            atomicAdd(&o_acc[(size_t)(rowbase + qB) * 32 + col],      vB0);
            atomicAdd(&o_acc[(size_t)(rowbase + qB) * 32 + 16 + col], vB1);
        }
        if (quad == 0) {
            float tA = lA + red[0][col * 33 + 32] + red[1][col * 33 + 32] + red[2][col * 33 + 32];
            float tB = lB + red[0][(16 + col) * 33 + 32] + red[1][(16 + col) * 33 + 32] + red[2][(16 + col) * 33 + 32];
            atomicAdd(&l_acc[rowbase + col],      tA);
            atomicAdd(&l_acc[rowbase + 16 + col], tB);
        }
    }
}

// ---------------------------------------------------------------------------
// Kernel 3: normalize + output projection + residual (fp32 weights).
// One wave per query: o[k] = o_acc/l ; out = gamma*(o@W4 + b4) + x
// ---------------------------------------------------------------------------
__global__ __launch_bounds__(256) void merge_kernel(
    const float* __restrict__ l_acc, const float* __restrict__ o_acc,
    const float* __restrict__ x,
    const float* __restrict__ W4, const float* __restrict__ b4,
    const float* __restrict__ gamma, float* __restrict__ out)
{
    __shared__ float oS[4][DV];
    int wave = threadIdx.x >> 6;
    int lane = threadIdx.x & 63;
    int row  = blockIdx.x * 4 + wave;     // < 18432 exactly

    float invL = 1.f / l_acc[row];
    if (lane < DV) {
        oS[wave][lane] = o_acc[(size_t)row * DV + lane] * invL;
    }
    __syncthreads();

    float dot = b4[lane];
    #pragma unroll
    for (int k = 0; k < DV; ++k) dot += oS[wave][k] * W4[k * 64 + lane];
    float gm  = gamma[0];
    float res = x[(size_t)row * 64 + lane];
    out[(size_t)row * 64 + lane] = gm * dot + res;
}

// ---------------------------------------------------------------------------
extern "C" void kernel_launch(void* const* d_in, const int* in_sizes, int n_in,
                              void* d_out, int out_size, void* d_ws, size_t ws_size,
                              hipStream_t stream) {
    const float* x     = (const float*)d_in[0];
    const float* W1    = (const float*)d_in[1];
    const float* b1    = (const float*)d_in[2];
    const float* W2    = (const float*)d_in[3];
    const float* b2    = (const float*)d_in[4];
    const float* W3    = (const float*)d_in[5];
    const float* b3    = (const float*)d_in[6];
    const float* W4    = (const float*)d_in[7];
    const float* b4    = (const float*)d_in[8];
    const float* gamma = (const float*)d_in[9];
    float* out = (float*)d_out;

    // Workspace: fx/gx/hT bf16 (1.18 MB each) + l_acc + o_acc = 5.97 MB total
    short* fx    = (short*)d_ws;                  // 589824 shorts
    short* gx    = fx + (size_t)ROWS * 32;        // 589824 shorts
    short* hT    = gx + (size_t)ROWS * 32;        // 589824 shorts
    float* l_acc = (float*)(hT + (size_t)ROWS * 32);   // 18432 floats
    float* o_acc = l_acc + ROWS;                  // 589824 floats

    // proj (+ zeroing of l_acc/o_acc): 576 blocks x 512 threads
    proj_kernel<<<ROWS / PB, 512, 0, stream>>>(
        x, W1, b1, W2, b2, W3, b3, fx, gx, hT, (float4*)l_acc);

    // attention: 576 query-tiles x 4 key-splits = 2304 blocks x 4 waves
    attn_kernel<<<QT * KS, 256, 0, stream>>>(fx, gx, hT, l_acc, o_acc);

    // merge: 18432 queries / 4 waves per block
    merge_kernel<<<ROWS / 4, 256, 0, stream>>>(l_acc, o_acc, x, W4, b4, gamma, out);
}